// Round 13
// baseline (159.252 us; speedup 1.0000x reference)
//
#include <hip/hip_runtime.h>
#include <cstdint>

#define B_    32
#define T_    2048
#define D_    80
#define T2_   511
#define NROW  16352      // B_*T2_
#define GK    720        // INPUT_DIM
#define CBD   512
#define CBS   1024
#define HMASK 8176       // 16352/2
#define HN    2621440    // B_*T_*D_/2
#define NP    16384      // padded rows
#define KB    23         // 736/32 k-blocks (k=720 is the norm-augment slot)
#define GLDS  (259*81*4) // gather LDS bytes

using bfrag = __attribute__((ext_vector_type(8))) short;   // 8 bf16 = 4 VGPR
using f32x4 = __attribute__((ext_vector_type(4))) float;
using s8    = __attribute__((ext_vector_type(8))) short;

__device__ inline ushort f2bf(float f){                    // RNE f32->bf16
  uint32_t u = __float_as_uint(f);
  uint32_t r = (u + 0x7FFFu + ((u >> 16) & 1u)) >> 16;
  return (ushort)r;
}
__device__ inline float bf2f(ushort h){ return __uint_as_float(((uint32_t)h) << 16); }

#define GLL16(gsrc, ldst) __builtin_amdgcn_global_load_lds( \
    (__attribute__((address_space(1))) void*)(gsrc), \
    (__attribute__((address_space(3))) void*)(ldst), 16, 0, 0)

// ---------------- threefry2x32 (exact JAX schedule) ----------------
__host__ __device__ inline uint32_t rotl_(uint32_t v, int d){ return (v<<d)|(v>>(32-d)); }

__host__ __device__ inline void tf2x32(uint32_t k0, uint32_t k1, uint32_t& x0, uint32_t& x1){
  uint32_t ks2 = k0 ^ k1 ^ 0x1BD11BDAu;
  x0 += k0; x1 += k1;
  const int r0[4] = {13,15,26,6}, r1[4] = {17,29,16,24};
#pragma unroll
  for (int i=0;i<4;i++){ x0 += x1; x1 = rotl_(x1, r0[i]); x1 ^= x0; }
  x0 += k1; x1 += ks2 + 1u;
#pragma unroll
  for (int i=0;i<4;i++){ x0 += x1; x1 = rotl_(x1, r1[i]); x1 ^= x0; }
  x0 += ks2; x1 += k0 + 2u;
#pragma unroll
  for (int i=0;i<4;i++){ x0 += x1; x1 = rotl_(x1, r0[i]); x1 ^= x0; }
  x0 += k0; x1 += k1 + 3u;
#pragma unroll
  for (int i=0;i<4;i++){ x0 += x1; x1 = rotl_(x1, r1[i]); x1 ^= x0; }
  x0 += k1; x1 += ks2 + 4u;
#pragma unroll
  for (int i=0;i<4;i++){ x0 += x1; x1 = rotl_(x1, r0[i]); x1 ^= x0; }
  x0 += ks2; x1 += k0 + 5u;
}

// XLA ErfInv32 (Giles) — matches lax.erf_inv f32
__device__ inline float erfinv_f(float x){
  float w = -log1pf(-x*x);
  float p;
  if (w < 5.0f){
    w -= 2.5f;
    p = 2.81022636e-08f;
    p = fmaf(p, w, 3.43273939e-07f);
    p = fmaf(p, w, -3.5233877e-06f);
    p = fmaf(p, w, -4.39150654e-06f);
    p = fmaf(p, w, 0.00021858087f);
    p = fmaf(p, w, -0.00125372503f);
    p = fmaf(p, w, -0.00417768164f);
    p = fmaf(p, w, 0.246640727f);
    p = fmaf(p, w, 1.50140941f);
  } else {
    w = sqrtf(w) - 3.0f;
    p = -0.000200214257f;
    p = fmaf(p, w, 0.000100950558f);
    p = fmaf(p, w, 0.00134934322f);
    p = fmaf(p, w, -0.00367342844f);
    p = fmaf(p, w, 0.00573950773f);
    p = fmaf(p, w, -0.0076224613f);
    p = fmaf(p, w, 0.00943887047f);
    p = fmaf(p, w, 1.00167406f);
    p = fmaf(p, w, 2.83297682f);
  }
  return p * x;
}

__device__ inline int label_len(int L){ return (((L - 3) / 2) - 2) / 2 + 1; }

// ---------------- kernel 1: gather via LDS-staged raw rows (coalesced HBM reads) ----------------
__global__ __launch_bounds__(256) void gather_k(const float* __restrict__ raw,
                                                ushort* __restrict__ S0, ushort* __restrict__ S1){
  extern __shared__ float lraw[];                // [259][81] padded
  int b = blockIdx.x >> 3, ch = blockIdx.x & 7;
  int t20 = ch * 64;
  int nt2 = (T2_ - t20 < 64) ? (T2_ - t20) : 64;
  int r0 = 4 * t20;
  int rows = (T_ - r0 < 259) ? (T_ - r0) : 259;
  int tid = threadIdx.x;
  const float4* gsrc = (const float4*)(raw + ((size_t)b*T_ + r0)*D_);
  int nf4 = rows * 20;                           // 80 floats/row = 20 float4
  for (int q = tid; q < nf4; q += 256){
    float4 v = gsrc[q];
    int row = q / 20, c4 = (q - row*20) * 4;
    float* dst = &lraw[row*81 + c4];
    dst[0]=v.x; dst[1]=v.y; dst[2]=v.z; dst[3]=v.w;
  }
  __syncthreads();
  int nl = tid >> 2, g = tid & 3;
  if (nl >= nt2) return;
  int n = b*T2_ + t20 + nl;
  int gs = g ^ ((n >> 1) & 3);                   // 16B-granule XOR swizzle
  for (int kb = 0; kb < KB; ++kb){
    s8 o0, o1;
#pragma unroll
    for (int j = 0; j < 8; ++j){
      int k = kb*32 + g*8 + j;
      float v = 0.f;
      if (k < GK){
        int d = k / 9, rem = k - 9*d;
        int k1 = rem / 3, k2 = rem - 3*k1;
        v = lraw[(4*nl + 2*k2 + k1)*81 + d];
      } else if (k == GK) v = 1.f;               // norm-augment slot
      ushort h0 = f2bf(v); ushort h1 = f2bf(v - bf2f(h0));
      o0[j] = (short)h0; o1[j] = (short)h1;
    }
    size_t off = ((size_t)kb*NP + n)*32 + gs*8;
    *(s8*)&S0[off] = o0;
    *(s8*)&S1[off] = o1;
  }
}

// ---------------- kernel 2a: Wp[kz] = P(720x512)*cb^T, split-K x4 (fp32) ----------------
__global__ __launch_bounds__(256) void wgemm_k(const float* __restrict__ P, const float* __restrict__ cb,
                                               float* __restrict__ Wp){
  __shared__ float sP[16][68];
  __shared__ float sC[16][68];
  int r0 = blockIdx.y * 64, c0 = blockIdx.x * 64;
  int kz = blockIdx.z;
  int tid = threadIdx.x, tx = tid & 15, ty = tid >> 4;
  float acc[4][4] = {};
  for (int k0 = kz * 128; k0 < kz * 128 + 128; k0 += 16){
    __syncthreads();
    {
      int r = tid >> 2, kq = tid & 3;
      int rr = r0 + r;
      float4 v = {0.f,0.f,0.f,0.f};
      if (rr < GK) v = *(const float4*)&P[rr * CBD + k0 + kq * 4];
      sP[kq*4+0][r] = v.x; sP[kq*4+1][r] = v.y; sP[kq*4+2][r] = v.z; sP[kq*4+3][r] = v.w;
      float4 w = *(const float4*)&cb[(c0 + r) * CBD + k0 + kq * 4];
      sC[kq*4+0][r] = w.x; sC[kq*4+1][r] = w.y; sC[kq*4+2][r] = w.z; sC[kq*4+3][r] = w.w;
    }
    __syncthreads();
#pragma unroll
    for (int kk = 0; kk < 16; ++kk){
      float4 a = *(const float4*)&sP[kk][ty * 4];
      float4 b = *(const float4*)&sC[kk][tx * 4];
      float av[4] = {a.x,a.y,a.z,a.w}, bv[4] = {b.x,b.y,b.z,b.w};
#pragma unroll
      for (int i = 0; i < 4; ++i)
#pragma unroll
        for (int j = 0; j < 4; ++j) acc[i][j] = fmaf(av[i], bv[j], acc[i][j]);
    }
  }
#pragma unroll
  for (int i = 0; i < 4; ++i){
    int r = r0 + ty * 4 + i;
    if (r < GK){
      float4 o; o.x = acc[i][0]; o.y = acc[i][1]; o.z = acc[i][2]; o.w = acc[i][3];
      *(float4*)&Wp[((size_t)kz * GK + r) * CBS + c0 + tx * 4] = o;
    }
  }
}

// ---------------- kernel 2b: reduce split-K + codebook norms (fused), swizzled panels ----------------
__global__ void wreduce_k(const float* __restrict__ Wp, const float* __restrict__ cb,
                          ushort* __restrict__ W0, ushort* __restrict__ W1){
  int bid = blockIdx.x;
  if (bid < (GK * CBS) / 256){
    int idx = bid * 256 + threadIdx.x;
    int r = idx >> 10, c = idx & (CBS - 1);
    float v = Wp[(size_t)r * CBS + c]
            + Wp[((size_t)GK + r) * CBS + c]
            + Wp[((size_t)2*GK + r) * CBS + c]
            + Wp[((size_t)3*GK + r) * CBS + c];
    ushort h0 = f2bf(v); ushort h1 = f2bf(v - bf2f(h0));
    size_t o = ((size_t)(r >> 5) * CBS + c) * 32 + ((r & 31) ^ (((c >> 1) & 3) << 3));
    W0[o] = h0; W1[o] = h1;
  } else {
    // codebook norms -> augment row (k=720..735) of last k-panel
    int c = (bid - (GK * CBS) / 256) * 4 + (threadIdx.x >> 6);
    int lane = threadIdx.x & 63;
    double s = 0.0;
    for (int k = lane; k < CBD; k += 64){ float v = cb[c*CBD + k]; s += (double)v * (double)v; }
#pragma unroll
    for (int off = 32; off; off >>= 1) s += __shfl_down(s, off);
    float nf = (float)s;
    nf = __shfl(nf, 0);
    size_t base = ((size_t)(KB-1)*CBS + c)*32;
    int sw = ((c >> 1) & 3) << 3;
    if (lane == 16){
      float h = -0.5f * nf;
      ushort h0 = f2bf(h); ushort h1 = f2bf(h - bf2f(h0));
      W0[base + (16 ^ sw)] = h0; W1[base + (16 ^ sw)] = h1;
    } else if (lane > 16 && lane < 32){
      W0[base + (lane ^ sw)] = 0; W1[base + (lane ^ sw)] = 0;
    }
  }
}

// ---------------- kernel 3: score = S*W, 128x128 tile, 8 waves, 2 blocks/CU ----------------
__global__ __launch_bounds__(512, 4) void score_k(const ushort* __restrict__ S0, const ushort* __restrict__ S1,
                                                  const ushort* __restrict__ W0, const ushort* __restrict__ W1,
                                                  float* __restrict__ pval, int* __restrict__ pidx){
  extern __shared__ ushort lds[];                // 2 bufs x 4 panels x 4096 ushorts = 64 KiB
  int tid = threadIdx.x;
  int lane = tid & 63, wid = tid >> 6;           // 8 waves
  int wm = wid >> 2, wn = wid & 3;               // 2x4 waves -> 64x32 per wave
  int g = lane >> 4, lr = lane & 15;
  int gsw = g ^ ((lr >> 1) & 3);                 // swizzled granule (lane-constant)

  // XCD-aware decode: 1024 blocks, 128 per XCD; 8 col-panels x 16 row-panels per XCD
  int id = blockIdx.x;
  int xcd = id & 7, slot = id >> 3;
  int cidx = slot & 7, ridx = (xcd << 4) | (slot >> 3);
  int n0 = ridx * 128, c0 = cidx * 128;

  // staging: panel p = wid>>1 (S0,S1,W0,W1), half h = wid&1; 4 GLL16/wave/kb
  int p = wid >> 1, h = wid & 1;
  const ushort* src0;
  size_t kstride;
  if      (p == 0){ src0 = S0 + (size_t)n0*32; kstride = (size_t)NP*32; }
  else if (p == 1){ src0 = S1 + (size_t)n0*32; kstride = (size_t)NP*32; }
  else if (p == 2){ src0 = W0 + (size_t)c0*32; kstride = (size_t)CBS*32; }
  else            { src0 = W1 + (size_t)c0*32; kstride = (size_t)CBS*32; }
  src0 += h * 2048;
  int doff = p * 4096 + h * 2048;

  f32x4 acc[4][2] = {};

  // prologue: stage kb=0 into buf 0
#pragma unroll
  for (int q = 0; q < 4; ++q) GLL16(src0 + q*512 + lane*8, lds + doff + q*512);

  int abase = (wm*64 + lr)*32 + gsw*8;
  int bbase = (wn*32 + lr)*32 + gsw*8;

  for (int kb = 0; kb < KB; ++kb){
    const ushort* cur = lds + (kb & 1) * 16384;
    ushort*       nxt = lds + ((kb & 1) ^ 1) * 16384;
    // cur's staging loads were issued a full kb earlier -> vmcnt(0) is ~free
    asm volatile("s_waitcnt vmcnt(0)" ::: "memory");
    __builtin_amdgcn_s_barrier();

    const ushort* A0 = cur;
    const ushort* A1 = cur + 4096;
    const ushort* B0 = cur + 8192;
    const ushort* B1 = cur + 12288;

    // ---- phase 1: a0 + b0 + b1 reads, issue next-tile staging, a0xb0 + a0xb1 ----
    bfrag a0f[4], b0f[2], b1f[2];
#pragma unroll
    for (int mt = 0; mt < 4; ++mt) a0f[mt] = *(const bfrag*)&A0[abase + mt*512];
#pragma unroll
    for (int nt = 0; nt < 2; ++nt){
      b0f[nt] = *(const bfrag*)&B0[bbase + nt*512];
      b1f[nt] = *(const bfrag*)&B1[bbase + nt*512];
    }
    if (kb + 1 < KB){
      const ushort* s = src0 + (size_t)(kb+1)*kstride;
#pragma unroll
      for (int q = 0; q < 4; ++q) GLL16(s + q*512 + lane*8, nxt + doff + q*512);
    }
    asm volatile("s_waitcnt lgkmcnt(0)" ::: "memory");
    __builtin_amdgcn_sched_barrier(0);
    __builtin_amdgcn_s_setprio(1);
#pragma unroll
    for (int mt = 0; mt < 4; ++mt)
#pragma unroll
      for (int nt = 0; nt < 2; ++nt)
        acc[mt][nt] = __builtin_amdgcn_mfma_f32_16x16x32_bf16(a0f[mt], b0f[nt], acc[mt][nt], 0,0,0);
#pragma unroll
    for (int mt = 0; mt < 4; ++mt)
#pragma unroll
      for (int nt = 0; nt < 2; ++nt)
        acc[mt][nt] = __builtin_amdgcn_mfma_f32_16x16x32_bf16(a0f[mt], b1f[nt], acc[mt][nt], 0,0,0);
    __builtin_amdgcn_s_setprio(0);
    __builtin_amdgcn_sched_barrier(0);
    // ---- phase 2: a1 reads, a1xb0 ----
    bfrag a1f[4];
#pragma unroll
    for (int mt = 0; mt < 4; ++mt) a1f[mt] = *(const bfrag*)&A1[abase + mt*512];
    asm volatile("s_waitcnt lgkmcnt(0)" ::: "memory");
    __builtin_amdgcn_sched_barrier(0);
    __builtin_amdgcn_s_setprio(1);
#pragma unroll
    for (int mt = 0; mt < 4; ++mt)
#pragma unroll
      for (int nt = 0; nt < 2; ++nt)
        acc[mt][nt] = __builtin_amdgcn_mfma_f32_16x16x32_bf16(a1f[mt], b0f[nt], acc[mt][nt], 0,0,0);
    __builtin_amdgcn_s_setprio(0);
    __builtin_amdgcn_sched_barrier(0);
    // kb-top vmcnt(0)+barrier provides the cur/nxt handoff
  }

  // epilogue: dist = -2*acc (norms folded); per-row argmin over this wave's 32 cols
#pragma unroll
  for (int mt = 0; mt < 4; ++mt){
    float bv[4]; int bi[4];
#pragma unroll
    for (int r = 0; r < 4; ++r){
      float best = 3.4e38f; int besti = 0;
#pragma unroll
      for (int nt = 0; nt < 2; ++nt){            // nt ascending == col ascending
        float d = -2.f * acc[mt][nt][r];
        int c = c0 + wn*32 + nt*16 + lr;
        if (d < best){ best = d; besti = c; }
      }
      bv[r] = best; bi[r] = besti;
    }
#pragma unroll
    for (int off = 1; off < 16; off <<= 1){
#pragma unroll
      for (int r = 0; r < 4; ++r){
        float ov = __shfl_xor(bv[r], off);
        int   oi = __shfl_xor(bi[r], off);
        if (ov < bv[r] || (ov == bv[r] && oi < bi[r])){ bv[r] = ov; bi[r] = oi; }
      }
    }
    if (lr == 0){
      int pp = cidx*4 + wn;
#pragma unroll
      for (int r = 0; r < 4; ++r){
        int n = n0 + wm*64 + mt*16 + g*4 + r;
        pval[(size_t)pp*NP + n] = bv[r];
        pidx[(size_t)pp*NP + n] = bi[r];
      }
    }
  }
}

// ---------------- kernel 4: fused mask (threefry, bit-exact) + combine 32 partials -> labels ----------------
__device__ inline void emit_mask(const int* len, float* md, int i, uint32_t bits){
  float u = __uint_as_float((bits >> 9) | 0x3F800000u) - 1.0f;
  int b = i / T2_, t2 = i - b * T2_;
  bool m = (u < 0.1f) && (t2 < label_len(len[b]));
  md[i] = m ? 1.0f : 0.0f;
}

__device__ inline void comb_one(const float* __restrict__ pval, const int* __restrict__ pidx,
                                const int* __restrict__ len, float* __restrict__ lb, int n){
  float bv = pval[n]; int bi = pidx[n];
#pragma unroll
  for (int p = 1; p < 32; ++p){
    float v = pval[(size_t)p*NP + n]; int ii = pidx[(size_t)p*NP + n];
    if (v < bv || (v == bv && ii < bi)){ bv = v; bi = ii; }
  }
  int b = n / T2_, t2 = n - b * T2_;
  lb[n] = (t2 < label_len(len[b])) ? (float)(bi + 1) : 0.f;
}

__global__ void maskcomb_k(const float* __restrict__ pval, const int* __restrict__ pidx,
                           const int* __restrict__ len, float* __restrict__ lb,
                           float* __restrict__ md, uint32_t km0, uint32_t km1){
  int j = blockIdx.x * 256 + threadIdx.x;
  if (j >= HMASK) return;
  uint32_t x0 = (uint32_t)j, x1 = (uint32_t)(j + HMASK);
  tf2x32(km0, km1, x0, x1);
  emit_mask(len, md, j, x0);
  emit_mask(len, md, j + HMASK, x1);
  comb_one(pval, pidx, len, lb, j);
  comb_one(pval, pidx, len, lb, j + HMASK);
}

// ---------------- kernel 5: masked_feats (float4; threefry normal bit-exact, only when masked) ----------------
__device__ inline bool frame_row_masked(const float* md, int b, int t){
  int lo = (t < 3) ? 0 : ((t - 3) >> 2);
  int hi = t >> 2; if (hi > T2_ - 1) hi = T2_ - 1;
  bool m = false;
  for (int t2 = lo; t2 <= hi; ++t2) m = m || (md[b * T2_ + t2] != 0.f);
  return m;
}

__device__ inline float noise_from_bits(uint32_t bits){
  float f = __uint_as_float((bits >> 9) | 0x3F800000u) - 1.0f;
  const float LOV = -0.99999994f;
  float u = fmaf(f, 2.0f, LOV);
  u = fmaxf(LOV, u);
  return 0.1f * (1.41421356f * erfinv_f(u));
}

__global__ void feats_k(const float* __restrict__ aug, const float* __restrict__ md,
                        float* __restrict__ mf, uint32_t kn0, uint32_t kn1){
  int q = blockIdx.x * 256 + threadIdx.x;        // float4 index in [0, HN/4)
  int e0 = q * 4;
  int row1 = e0 / D_;                            // 80 | e0..e0+3 stay in one row (80%4==0)
  int t1 = row1 & (T_ - 1), b1 = row1 >> 11;
  int e2 = e0 + HN;
  int row2 = e2 / D_;
  int t2 = row2 & (T_ - 1), b2 = row2 >> 11;
  bool m1 = frame_row_masked(md, b1, t1);
  bool m2 = frame_row_masked(md, b2, t2);
  const float4* aug4 = (const float4*)aug;
  float4* mf4 = (float4*)mf;
  float4 o1 = aug4[q];
  float4 o2 = aug4[q + HN/4];
  if (m1 | m2){
    uint32_t xs[4], ys[4];
#pragma unroll
    for (int i = 0; i < 4; ++i){
      uint32_t x0 = (uint32_t)(e0 + i), x1 = (uint32_t)(e0 + i + HN);
      tf2x32(kn0, kn1, x0, x1);
      xs[i] = x0; ys[i] = x1;
    }
    if (m1){ o1.x = noise_from_bits(xs[0]); o1.y = noise_from_bits(xs[1]);
             o1.z = noise_from_bits(xs[2]); o1.w = noise_from_bits(xs[3]); }
    if (m2){ o2.x = noise_from_bits(ys[0]); o2.y = noise_from_bits(ys[1]);
             o2.z = noise_from_bits(ys[2]); o2.w = noise_from_bits(ys[3]); }
  }
  mf4[q] = o1;
  mf4[q + HN/4] = o2;
}

// ---------------- host ----------------
extern "C" void kernel_launch(void* const* d_in, const int* in_sizes, int n_in,
                              void* d_out, int out_size, void* d_ws, size_t ws_size,
                              hipStream_t stream){
  const float* raw  = (const float*)d_in[0];
  const float* aug  = (const float*)d_in[1];
  const int*   len  = (const int*)  d_in[2];
  const float* proj = (const float*)d_in[3];
  const float* cb   = (const float*)d_in[4];

  float* out = (float*)d_out;
  float* mf  = out;                       // (B,T,D)   5,242,880
  float* lb  = out + 5242880;             // (1,B,T2)     16,352
  float* md  = out + 5259232;             // (B,T2)       16,352

  ushort* w  = (ushort*)d_ws;
  ushort* W0 = w;                                   // KB*CBS*32 = 753,664 ushorts
  ushort* W1 = W0 + (size_t)KB*CBS*32;
  ushort* S0 = W1 + (size_t)KB*CBS*32;              // KB*NP*32 = 12,058,624 ushorts
  ushort* S1 = S0 + (size_t)KB*NP*32;
  float* pval = (float*)(S1 + (size_t)KB*NP*32);    // 32*NP floats
  int*   pidx = (int*)(pval + (size_t)32*NP);       // 32*NP ints
  float* Wp   = (float*)(pidx + (size_t)32*NP);     // 4*GK*CBS floats = 11.8MB

  // raise dynamic LDS caps (idempotent host-side attribute sets)
  hipFuncSetAttribute((const void*)score_k,  hipFuncAttributeMaxDynamicSharedMemorySize, 65536);
  hipFuncSetAttribute((const void*)gather_k, hipFuncAttributeMaxDynamicSharedMemorySize, GLDS);

  // JAX: key(42) -> split -> (km, kn)
  uint32_t a0 = 0u, a1 = 2u, b0 = 1u, b1 = 3u;
  tf2x32(0u, 42u, a0, a1);
  tf2x32(0u, 42u, b0, b1);
  uint32_t km0 = a0, km1 = b0, kn0 = a1, kn1 = b1;

  wgemm_k<<<dim3(CBS / 64, 12, 4), 256, 0, stream>>>(proj, cb, Wp);
  wreduce_k<<<(GK * CBS) / 256 + CBS / 4, 256, 0, stream>>>(Wp, cb, W0, W1);
  gather_k<<<256, 256, GLDS, stream>>>(raw, S0, S1);
  score_k<<<1024, 512, 65536, stream>>>(S0, S1, W0, W1, pval, pidx);
  maskcomb_k<<<(HMASK + 255) / 256, 256, 0, stream>>>(pval, pidx, len, lb, md, km0, km1);
  feats_k<<<HN / 4 / 256, 256, 0, stream>>>(aug, md, mf, kn0, kn1);
}

// Round 14
// 145.739 us; speedup vs baseline: 1.0927x; 1.0927x over previous
//
#include <hip/hip_runtime.h>
#include <cstdint>

#define B_    32
#define T_    2048
#define D_    80
#define T2_   511
#define NROW  16352      // B_*T2_
#define GK    720        // INPUT_DIM
#define CBD   512
#define CBS   1024
#define HMASK 8176       // 16352/2
#define HN    2621440    // B_*T_*D_/2
#define NP    16384      // padded rows
#define KB    23         // 736/32 k-blocks (k=720 is the norm-augment slot)
#define GLDS  (259*81*4) // gather LDS bytes

using bfrag = __attribute__((ext_vector_type(8))) short;   // 8 bf16 = 4 VGPR
using f32x4 = __attribute__((ext_vector_type(4))) float;
using s8    = __attribute__((ext_vector_type(8))) short;

__device__ inline ushort f2bf(float f){                    // RNE f32->bf16
  uint32_t u = __float_as_uint(f);
  uint32_t r = (u + 0x7FFFu + ((u >> 16) & 1u)) >> 16;
  return (ushort)r;
}
__device__ inline float bf2f(ushort h){ return __uint_as_float(((uint32_t)h) << 16); }

#define GLL16(gsrc, ldst) __builtin_amdgcn_global_load_lds( \
    (__attribute__((address_space(1))) void*)(gsrc), \
    (__attribute__((address_space(3))) void*)(ldst), 16, 0, 0)

// ---------------- threefry2x32 (exact JAX schedule) ----------------
__host__ __device__ inline uint32_t rotl_(uint32_t v, int d){ return (v<<d)|(v>>(32-d)); }

__host__ __device__ inline void tf2x32(uint32_t k0, uint32_t k1, uint32_t& x0, uint32_t& x1){
  uint32_t ks2 = k0 ^ k1 ^ 0x1BD11BDAu;
  x0 += k0; x1 += k1;
  const int r0[4] = {13,15,26,6}, r1[4] = {17,29,16,24};
#pragma unroll
  for (int i=0;i<4;i++){ x0 += x1; x1 = rotl_(x1, r0[i]); x1 ^= x0; }
  x0 += k1; x1 += ks2 + 1u;
#pragma unroll
  for (int i=0;i<4;i++){ x0 += x1; x1 = rotl_(x1, r1[i]); x1 ^= x0; }
  x0 += ks2; x1 += k0 + 2u;
#pragma unroll
  for (int i=0;i<4;i++){ x0 += x1; x1 = rotl_(x1, r0[i]); x1 ^= x0; }
  x0 += k0; x1 += k1 + 3u;
#pragma unroll
  for (int i=0;i<4;i++){ x0 += x1; x1 = rotl_(x1, r1[i]); x1 ^= x0; }
  x0 += k1; x1 += ks2 + 4u;
#pragma unroll
  for (int i=0;i<4;i++){ x0 += x1; x1 = rotl_(x1, r0[i]); x1 ^= x0; }
  x0 += ks2; x1 += k0 + 5u;
}

// XLA ErfInv32 (Giles) — matches lax.erf_inv f32
__device__ inline float erfinv_f(float x){
  float w = -log1pf(-x*x);
  float p;
  if (w < 5.0f){
    w -= 2.5f;
    p = 2.81022636e-08f;
    p = fmaf(p, w, 3.43273939e-07f);
    p = fmaf(p, w, -3.5233877e-06f);
    p = fmaf(p, w, -4.39150654e-06f);
    p = fmaf(p, w, 0.00021858087f);
    p = fmaf(p, w, -0.00125372503f);
    p = fmaf(p, w, -0.00417768164f);
    p = fmaf(p, w, 0.246640727f);
    p = fmaf(p, w, 1.50140941f);
  } else {
    w = sqrtf(w) - 3.0f;
    p = -0.000200214257f;
    p = fmaf(p, w, 0.000100950558f);
    p = fmaf(p, w, 0.00134934322f);
    p = fmaf(p, w, -0.00367342844f);
    p = fmaf(p, w, 0.00573950773f);
    p = fmaf(p, w, -0.0076224613f);
    p = fmaf(p, w, 0.00943887047f);
    p = fmaf(p, w, 1.00167406f);
    p = fmaf(p, w, 2.83297682f);
  }
  return p * x;
}

__device__ inline int label_len(int L){ return (((L - 3) / 2) - 2) / 2 + 1; }

// ---------------- kernel 1: gather via LDS-staged raw rows (coalesced HBM reads) ----------------
__global__ __launch_bounds__(256) void gather_k(const float* __restrict__ raw,
                                                ushort* __restrict__ S0, ushort* __restrict__ S1){
  extern __shared__ float lraw[];                // [259][81] padded
  int b = blockIdx.x >> 3, ch = blockIdx.x & 7;
  int t20 = ch * 64;
  int nt2 = (T2_ - t20 < 64) ? (T2_ - t20) : 64;
  int r0 = 4 * t20;
  int rows = (T_ - r0 < 259) ? (T_ - r0) : 259;
  int tid = threadIdx.x;
  const float4* gsrc = (const float4*)(raw + ((size_t)b*T_ + r0)*D_);
  int nf4 = rows * 20;                           // 80 floats/row = 20 float4
  for (int q = tid; q < nf4; q += 256){
    float4 v = gsrc[q];
    int row = q / 20, c4 = (q - row*20) * 4;
    float* dst = &lraw[row*81 + c4];
    dst[0]=v.x; dst[1]=v.y; dst[2]=v.z; dst[3]=v.w;
  }
  __syncthreads();
  int nl = tid >> 2, g = tid & 3;
  if (nl >= nt2) return;
  int n = b*T2_ + t20 + nl;
  int gs = g ^ ((n >> 1) & 3);                   // 16B-granule XOR swizzle
  for (int kb = 0; kb < KB; ++kb){
    s8 o0, o1;
#pragma unroll
    for (int j = 0; j < 8; ++j){
      int k = kb*32 + g*8 + j;
      float v = 0.f;
      if (k < GK){
        int d = k / 9, rem = k - 9*d;
        int k1 = rem / 3, k2 = rem - 3*k1;
        v = lraw[(4*nl + 2*k2 + k1)*81 + d];
      } else if (k == GK) v = 1.f;               // norm-augment slot
      ushort h0 = f2bf(v); ushort h1 = f2bf(v - bf2f(h0));
      o0[j] = (short)h0; o1[j] = (short)h1;
    }
    size_t off = ((size_t)kb*NP + n)*32 + gs*8;
    *(s8*)&S0[off] = o0;
    *(s8*)&S1[off] = o1;
  }
}

// ---------------- kernel 2a: Wp[kz] = P(720x512)*cb^T, split-K x4 (fp32) ----------------
__global__ __launch_bounds__(256) void wgemm_k(const float* __restrict__ P, const float* __restrict__ cb,
                                               float* __restrict__ Wp){
  __shared__ float sP[16][68];
  __shared__ float sC[16][68];
  int r0 = blockIdx.y * 64, c0 = blockIdx.x * 64;
  int kz = blockIdx.z;
  int tid = threadIdx.x, tx = tid & 15, ty = tid >> 4;
  float acc[4][4] = {};
  for (int k0 = kz * 128; k0 < kz * 128 + 128; k0 += 16){
    __syncthreads();
    {
      int r = tid >> 2, kq = tid & 3;
      int rr = r0 + r;
      float4 v = {0.f,0.f,0.f,0.f};
      if (rr < GK) v = *(const float4*)&P[rr * CBD + k0 + kq * 4];
      sP[kq*4+0][r] = v.x; sP[kq*4+1][r] = v.y; sP[kq*4+2][r] = v.z; sP[kq*4+3][r] = v.w;
      float4 w = *(const float4*)&cb[(c0 + r) * CBD + k0 + kq * 4];
      sC[kq*4+0][r] = w.x; sC[kq*4+1][r] = w.y; sC[kq*4+2][r] = w.z; sC[kq*4+3][r] = w.w;
    }
    __syncthreads();
#pragma unroll
    for (int kk = 0; kk < 16; ++kk){
      float4 a = *(const float4*)&sP[kk][ty * 4];
      float4 b = *(const float4*)&sC[kk][tx * 4];
      float av[4] = {a.x,a.y,a.z,a.w}, bv[4] = {b.x,b.y,b.z,b.w};
#pragma unroll
      for (int i = 0; i < 4; ++i)
#pragma unroll
        for (int j = 0; j < 4; ++j) acc[i][j] = fmaf(av[i], bv[j], acc[i][j]);
    }
  }
#pragma unroll
  for (int i = 0; i < 4; ++i){
    int r = r0 + ty * 4 + i;
    if (r < GK){
      float4 o; o.x = acc[i][0]; o.y = acc[i][1]; o.z = acc[i][2]; o.w = acc[i][3];
      *(float4*)&Wp[((size_t)kz * GK + r) * CBS + c0 + tx * 4] = o;
    }
  }
}

// ---------------- kernel 2b: reduce split-K + codebook norms (fused), swizzled panels ----------------
__global__ void wreduce_k(const float* __restrict__ Wp, const float* __restrict__ cb,
                          ushort* __restrict__ W0, ushort* __restrict__ W1){
  int bid = blockIdx.x;
  if (bid < (GK * CBS) / 256){
    int idx = bid * 256 + threadIdx.x;
    int r = idx >> 10, c = idx & (CBS - 1);
    float v = Wp[(size_t)r * CBS + c]
            + Wp[((size_t)GK + r) * CBS + c]
            + Wp[((size_t)2*GK + r) * CBS + c]
            + Wp[((size_t)3*GK + r) * CBS + c];
    ushort h0 = f2bf(v); ushort h1 = f2bf(v - bf2f(h0));
    size_t o = ((size_t)(r >> 5) * CBS + c) * 32 + ((r & 31) ^ (((c >> 1) & 3) << 3));
    W0[o] = h0; W1[o] = h1;
  } else {
    // codebook norms -> augment row (k=720..735) of last k-panel
    int c = (bid - (GK * CBS) / 256) * 4 + (threadIdx.x >> 6);
    int lane = threadIdx.x & 63;
    double s = 0.0;
    for (int k = lane; k < CBD; k += 64){ float v = cb[c*CBD + k]; s += (double)v * (double)v; }
#pragma unroll
    for (int off = 32; off; off >>= 1) s += __shfl_down(s, off);
    float nf = (float)s;
    nf = __shfl(nf, 0);
    size_t base = ((size_t)(KB-1)*CBS + c)*32;
    int sw = ((c >> 1) & 3) << 3;
    if (lane == 16){
      float h = -0.5f * nf;
      ushort h0 = f2bf(h); ushort h1 = f2bf(h - bf2f(h0));
      W0[base + (16 ^ sw)] = h0; W1[base + (16 ^ sw)] = h1;
    } else if (lane > 16 && lane < 32){
      W0[base + (lane ^ sw)] = 0; W1[base + (lane ^ sw)] = 0;
    }
  }
}

// ---------------- kernel 3: score = S*W, 256x256 tile, 6-phase register pipeline ----------------
__global__ __launch_bounds__(512, 2) void score_k(const ushort* __restrict__ S0, const ushort* __restrict__ S1,
                                                  const ushort* __restrict__ W0, const ushort* __restrict__ W1,
                                                  float* __restrict__ pval, int* __restrict__ pidx){
  extern __shared__ ushort lds[];                // 2 bufs x 4 panels x 8192 ushorts = 128 KiB
  int tid = threadIdx.x;
  int lane = tid & 63, wid = tid >> 6;           // 8 waves
  int wm = wid >> 2, wn = wid & 3;               // 2x4 waves -> 128x64 per wave
  int g = lane >> 4, lr = lane & 15;
  int gsw = g ^ ((lr >> 1) & 3);                 // swizzled granule (lane-constant)

  // XCD-aware decode
  int id = blockIdx.x;
  int xcd = id & 7, slot = id >> 3;
  int cidx = slot & 3, ridx = (xcd << 3) | (slot >> 2);
  int n0 = ridx * 256, c0 = cidx * 256;

  // staging: panel p = wid>>1 (S0,S1,W0,W1), half h = wid&1; 8 GLL16/wave/kb
  int p = wid >> 1, h = wid & 1;
  const ushort* src0;
  size_t kstride;
  if      (p == 0){ src0 = S0 + (size_t)n0*32; kstride = (size_t)NP*32; }
  else if (p == 1){ src0 = S1 + (size_t)n0*32; kstride = (size_t)NP*32; }
  else if (p == 2){ src0 = W0 + (size_t)c0*32; kstride = (size_t)CBS*32; }
  else            { src0 = W1 + (size_t)c0*32; kstride = (size_t)CBS*32; }
  src0 += h * 4096;
  int doff = p * 8192 + h * 4096;

  f32x4 acc[8][4] = {};

  // prologue: stage kb=0 into buf 0
#pragma unroll
  for (int q = 0; q < 8; ++q) GLL16(src0 + q*512 + lane*8, lds + doff + q*512);

  int abase = (wm*128 + lr)*32 + gsw*8;
  int bbase = (wn*64  + lr)*32 + gsw*8;

  for (int kb = 0; kb < KB; ++kb){
    const ushort* cur = lds + (kb & 1) * 32768;
    ushort*       nxt = lds + ((kb & 1) ^ 1) * 32768;

    __builtin_amdgcn_s_barrier();                 // all waves done reading prev buffer
    if (kb + 1 < KB){
      const ushort* s = src0 + (size_t)(kb+1)*kstride;
#pragma unroll
      for (int q = 0; q < 8; ++q) GLL16(s + q*512 + lane*8, nxt + doff + q*512);
      asm volatile("s_waitcnt vmcnt(8)" ::: "memory");   // cur's 8 loads (1 kb old) done
    } else {
      asm volatile("s_waitcnt vmcnt(0)" ::: "memory");
    }
    __builtin_amdgcn_s_barrier();                 // cur published to all waves

    const ushort* A0 = cur;
    const ushort* A1 = cur + 8192;
    const ushort* B0 = cur + 16384;
    const ushort* B1 = cur + 24576;

    bfrag a0lo[4], a0hi[4], a1lo[4], a1hi[4], b0f[4], b1f[4];
    // pre-reads: b0 + a0lo (consumed in ph0)
#pragma unroll
    for (int nt = 0; nt < 4; ++nt) b0f[nt] = *(const bfrag*)&B0[bbase + nt*512];
#pragma unroll
    for (int mt = 0; mt < 4; ++mt) a0lo[mt] = *(const bfrag*)&A0[abase + mt*512];
    // ---- ph0: issue b1 reads; MFMA a0lo x b0 -> acc[0-3] pass1 ----
#pragma unroll
    for (int nt = 0; nt < 4; ++nt) b1f[nt] = *(const bfrag*)&B1[bbase + nt*512];
    __builtin_amdgcn_sched_barrier(0);
    __builtin_amdgcn_s_setprio(1);
#pragma unroll
    for (int mt = 0; mt < 4; ++mt)
#pragma unroll
      for (int nt = 0; nt < 4; ++nt)
        acc[mt][nt] = __builtin_amdgcn_mfma_f32_16x16x32_bf16(a0lo[mt], b0f[nt], acc[mt][nt], 0,0,0);
    __builtin_amdgcn_s_setprio(0);
    __builtin_amdgcn_sched_barrier(0);
    // ---- ph1: issue a1lo reads; MFMA a0lo x b1 -> acc[0-3] pass2 ----
#pragma unroll
    for (int mt = 0; mt < 4; ++mt) a1lo[mt] = *(const bfrag*)&A1[abase + mt*512];
    __builtin_amdgcn_sched_barrier(0);
    __builtin_amdgcn_s_setprio(1);
#pragma unroll
    for (int mt = 0; mt < 4; ++mt)
#pragma unroll
      for (int nt = 0; nt < 4; ++nt)
        acc[mt][nt] = __builtin_amdgcn_mfma_f32_16x16x32_bf16(a0lo[mt], b1f[nt], acc[mt][nt], 0,0,0);
    __builtin_amdgcn_s_setprio(0);
    __builtin_amdgcn_sched_barrier(0);
    // ---- ph2: issue a0hi reads; MFMA a1lo x b0 -> acc[0-3] pass3 ----
#pragma unroll
    for (int mt = 0; mt < 4; ++mt) a0hi[mt] = *(const bfrag*)&A0[abase + (mt+4)*512];
    __builtin_amdgcn_sched_barrier(0);
    __builtin_amdgcn_s_setprio(1);
#pragma unroll
    for (int mt = 0; mt < 4; ++mt)
#pragma unroll
      for (int nt = 0; nt < 4; ++nt)
        acc[mt][nt] = __builtin_amdgcn_mfma_f32_16x16x32_bf16(a1lo[mt], b0f[nt], acc[mt][nt], 0,0,0);
    __builtin_amdgcn_s_setprio(0);
    __builtin_amdgcn_sched_barrier(0);
    // ---- ph3: issue a1hi reads; MFMA a0hi x b0 -> acc[4-7] pass1 ----
#pragma unroll
    for (int mt = 0; mt < 4; ++mt) a1hi[mt] = *(const bfrag*)&A1[abase + (mt+4)*512];
    __builtin_amdgcn_sched_barrier(0);
    __builtin_amdgcn_s_setprio(1);
#pragma unroll
    for (int mt = 0; mt < 4; ++mt)
#pragma unroll
      for (int nt = 0; nt < 4; ++nt)
        acc[4+mt][nt] = __builtin_amdgcn_mfma_f32_16x16x32_bf16(a0hi[mt], b0f[nt], acc[4+mt][nt], 0,0,0);
    __builtin_amdgcn_s_setprio(0);
    __builtin_amdgcn_sched_barrier(0);
    // ---- ph4: MFMA a0hi x b1 -> acc[4-7] pass2 ----
    __builtin_amdgcn_s_setprio(1);
#pragma unroll
    for (int mt = 0; mt < 4; ++mt)
#pragma unroll
      for (int nt = 0; nt < 4; ++nt)
        acc[4+mt][nt] = __builtin_amdgcn_mfma_f32_16x16x32_bf16(a0hi[mt], b1f[nt], acc[4+mt][nt], 0,0,0);
    __builtin_amdgcn_s_setprio(0);
    __builtin_amdgcn_sched_barrier(0);
    // ---- ph5: MFMA a1hi x b0 -> acc[4-7] pass3 ----
    __builtin_amdgcn_s_setprio(1);
#pragma unroll
    for (int mt = 0; mt < 4; ++mt)
#pragma unroll
      for (int nt = 0; nt < 4; ++nt)
        acc[4+mt][nt] = __builtin_amdgcn_mfma_f32_16x16x32_bf16(a1hi[mt], b0f[nt], acc[4+mt][nt], 0,0,0);
    __builtin_amdgcn_s_setprio(0);
    __builtin_amdgcn_sched_barrier(0);
  }

  // epilogue: dist = -2*acc (norms folded); per-row argmin over this wave's 64 cols
#pragma unroll
  for (int mt = 0; mt < 8; ++mt){
    float bv[4]; int bi[4];
#pragma unroll
    for (int r = 0; r < 4; ++r){
      float best = 3.4e38f; int besti = 0;
#pragma unroll
      for (int nt = 0; nt < 4; ++nt){            // nt ascending == col ascending
        float d = -2.f * acc[mt][nt][r];
        int c = c0 + wn*64 + nt*16 + lr;
        if (d < best){ best = d; besti = c; }
      }
      bv[r] = best; bi[r] = besti;
    }
#pragma unroll
    for (int off = 1; off < 16; off <<= 1){
#pragma unroll
      for (int r = 0; r < 4; ++r){
        float ov = __shfl_xor(bv[r], off);
        int   oi = __shfl_xor(bi[r], off);
        if (ov < bv[r] || (ov == bv[r] && oi < bi[r])){ bv[r] = ov; bi[r] = oi; }
      }
    }
    if (lr == 0){
      int pp = cidx*4 + wn;
#pragma unroll
      for (int r = 0; r < 4; ++r){
        int n = n0 + wm*128 + mt*16 + g*4 + r;
        pval[(size_t)pp*NP + n] = bv[r];
        pidx[(size_t)pp*NP + n] = bi[r];
      }
    }
  }
}

// ---------------- kernel 4: fused mask (threefry, bit-exact) + combine 16 partials -> labels ----------------
__device__ inline void emit_mask(const int* len, float* md, int i, uint32_t bits){
  float u = __uint_as_float((bits >> 9) | 0x3F800000u) - 1.0f;
  int b = i / T2_, t2 = i - b * T2_;
  bool m = (u < 0.1f) && (t2 < label_len(len[b]));
  md[i] = m ? 1.0f : 0.0f;
}

__device__ inline void comb_one(const float* __restrict__ pval, const int* __restrict__ pidx,
                                const int* __restrict__ len, float* __restrict__ lb, int n){
  float bv = pval[n]; int bi = pidx[n];
#pragma unroll
  for (int p = 1; p < 16; ++p){
    float v = pval[(size_t)p*NP + n]; int ii = pidx[(size_t)p*NP + n];
    if (v < bv || (v == bv && ii < bi)){ bv = v; bi = ii; }
  }
  int b = n / T2_, t2 = n - b * T2_;
  lb[n] = (t2 < label_len(len[b])) ? (float)(bi + 1) : 0.f;
}

__global__ void maskcomb_k(const float* __restrict__ pval, const int* __restrict__ pidx,
                           const int* __restrict__ len, float* __restrict__ lb,
                           float* __restrict__ md, uint32_t km0, uint32_t km1){
  int j = blockIdx.x * 256 + threadIdx.x;
  if (j >= HMASK) return;
  uint32_t x0 = (uint32_t)j, x1 = (uint32_t)(j + HMASK);
  tf2x32(km0, km1, x0, x1);
  emit_mask(len, md, j, x0);
  emit_mask(len, md, j + HMASK, x1);
  comb_one(pval, pidx, len, lb, j);
  comb_one(pval, pidx, len, lb, j + HMASK);
}

// ---------------- kernel 5: masked_feats (threefry normal, bit-exact; PRNG only when masked) ----------------
__device__ inline bool frame_masked(const float* md, int i){
  int tabs = i / D_;
  int t = tabs & (T_ - 1);
  int b = i / (D_ * T_);
  int lo = (t < 3) ? 0 : ((t - 3) >> 2);
  int hi = t >> 2; if (hi > T2_ - 1) hi = T2_ - 1;
  bool m = false;
  for (int t2 = lo; t2 <= hi; ++t2) m = m || (md[b * T2_ + t2] != 0.f);
  return m;
}

__device__ inline float noise_from_bits(uint32_t bits){
  float f = __uint_as_float((bits >> 9) | 0x3F800000u) - 1.0f;
  const float LOV = -0.99999994f;
  float u = fmaf(f, 2.0f, LOV);
  u = fmaxf(LOV, u);
  return 0.1f * (1.41421356f * erfinv_f(u));
}

__global__ void feats_k(const float* __restrict__ aug, const float* __restrict__ md,
                        float* __restrict__ mf, uint32_t kn0, uint32_t kn1){
  int j = blockIdx.x * 256 + threadIdx.x;
  bool m1 = frame_masked(md, j);
  bool m2 = frame_masked(md, j + HN);
  if (m1 || m2){
    uint32_t x0 = (uint32_t)j, x1 = (uint32_t)(j + HN);
    tf2x32(kn0, kn1, x0, x1);
    mf[j]      = m1 ? noise_from_bits(x0) : aug[j];
    mf[j + HN] = m2 ? noise_from_bits(x1) : aug[j + HN];
  } else {
    mf[j]      = aug[j];
    mf[j + HN] = aug[j + HN];
  }
}

// ---------------- host ----------------
extern "C" void kernel_launch(void* const* d_in, const int* in_sizes, int n_in,
                              void* d_out, int out_size, void* d_ws, size_t ws_size,
                              hipStream_t stream){
  const float* raw  = (const float*)d_in[0];
  const float* aug  = (const float*)d_in[1];
  const int*   len  = (const int*)  d_in[2];
  const float* proj = (const float*)d_in[3];
  const float* cb   = (const float*)d_in[4];

  float* out = (float*)d_out;
  float* mf  = out;                       // (B,T,D)   5,242,880
  float* lb  = out + 5242880;             // (1,B,T2)     16,352
  float* md  = out + 5259232;             // (B,T2)       16,352

  ushort* w  = (ushort*)d_ws;
  ushort* W0 = w;                                   // KB*CBS*32 = 753,664 ushorts
  ushort* W1 = W0 + (size_t)KB*CBS*32;
  ushort* S0 = W1 + (size_t)KB*CBS*32;              // KB*NP*32 = 12,058,624 ushorts
  ushort* S1 = S0 + (size_t)KB*NP*32;
  float* pval = (float*)(S1 + (size_t)KB*NP*32);    // 16*NP floats
  int*   pidx = (int*)(pval + (size_t)16*NP);       // 16*NP ints
  float* Wp   = (float*)(pidx + (size_t)16*NP);     // 4*GK*CBS floats = 11.8MB

  // raise dynamic LDS caps (idempotent host-side attribute sets)
  hipFuncSetAttribute((const void*)score_k,  hipFuncAttributeMaxDynamicSharedMemorySize, 131072);
  hipFuncSetAttribute((const void*)gather_k, hipFuncAttributeMaxDynamicSharedMemorySize, GLDS);

  // JAX: key(42) -> split -> (km, kn)
  uint32_t a0 = 0u, a1 = 2u, b0 = 1u, b1 = 3u;
  tf2x32(0u, 42u, a0, a1);
  tf2x32(0u, 42u, b0, b1);
  uint32_t km0 = a0, km1 = b0, kn0 = a1, kn1 = b1;

  wgemm_k<<<dim3(CBS / 64, 12, 4), 256, 0, stream>>>(proj, cb, Wp);
  wreduce_k<<<(GK * CBS) / 256 + CBS / 4, 256, 0, stream>>>(Wp, cb, W0, W1);
  gather_k<<<256, 256, GLDS, stream>>>(raw, S0, S1);
  score_k<<<256, 512, 131072, stream>>>(S0, S1, W0, W1, pval, pidx);
  maskcomb_k<<<(HMASK + 255) / 256, 256, 0, stream>>>(pval, pidx, len, lb, md, km0, km1);
  feats_k<<<HN / 256, 256, 0, stream>>>(aug, md, mf, kn0, kn1);
}